// Round 1
// baseline (279.321 us; speedup 1.0000x reference)
//
#include <hip/hip_runtime.h>

#define XDIM 45
#define XCDIM 10
#define ROWS_PER_BLOCK 256
#define BLOCK 256

__global__ __launch_bounds__(BLOCK) void twohot_argmax_kernel(
    const float* __restrict__ x,
    const float* __restrict__ table,
    float* __restrict__ out,
    int batch)
{
    // 256 rows * 45 floats = 11520 floats = 46080 B; reused for output staging
    __shared__ float lds_tile[ROWS_PER_BLOCK * XDIM];
    __shared__ float lds_table[XDIM * XCDIM]; // 450 floats

    const int tid = threadIdx.x;
    const long long block_row = (long long)blockIdx.x * ROWS_PER_BLOCK;
    const int rows_here = (int)min((long long)ROWS_PER_BLOCK, (long long)batch - block_row);

    // load two-hot table into LDS (450 floats)
    for (int i = tid; i < XDIM * XCDIM; i += BLOCK)
        lds_table[i] = table[i];

    // stage x tile into LDS, coalesced float4 loads.
    // tile base byte offset = blockIdx * 46080, 16B-aligned.
    const int tile_f4 = (rows_here * XDIM) / 4;          // full blocks: 2880
    const int tile_rem = (rows_here * XDIM) & 3;         // full blocks: 0
    const float4* __restrict__ xin = (const float4*)(x + block_row * XDIM);
    float4* ldsv = (float4*)lds_tile;
    #pragma unroll
    for (int it = 0; it < (ROWS_PER_BLOCK * XDIM) / (4 * BLOCK) + 1; ++it) {
        int i = tid + it * BLOCK;
        if (i < tile_f4)
            ldsv[i] = xin[i];
    }
    if (tid < tile_rem) { // tail floats for a partial last block (never hit at BATCH=1M)
        int i = tile_f4 * 4 + tid;
        lds_tile[i] = (x + block_row * XDIM)[i];
    }
    __syncthreads();

    // per-thread argmax over its own row (first-occurrence max, like jnp.argmax)
    float vals[XCDIM];
    if (tid < rows_here) {
        const float* row = lds_tile + tid * XDIM; // stride 45 floats: odd -> free 2-way LDS aliasing
        float m = row[0];
        int idx = 0;
        #pragma unroll
        for (int k = 1; k < XDIM; ++k) {
            float v = row[k];
            if (v > m) { m = v; idx = k; }
        }
        #pragma unroll
        for (int j = 0; j < XCDIM; ++j)
            vals[j] = lds_table[idx * XCDIM + j];
    }

    __syncthreads(); // all reads of in-tile done before reuse

    if (tid < rows_here) {
        #pragma unroll
        for (int j = 0; j < XCDIM; ++j)
            lds_tile[tid * XCDIM + j] = vals[j];
    }

    __syncthreads();

    // coalesced store: rows_here*10 floats (full blocks: 2560 = 640 float4)
    float4* __restrict__ outv = (float4*)(out + block_row * XCDIM);
    const int out_f4 = (rows_here * XCDIM) / 4;
    const int out_rem = (rows_here * XCDIM) & 3;
    const float4* ldso = (const float4*)lds_tile;
    #pragma unroll
    for (int it = 0; it < (ROWS_PER_BLOCK * XCDIM) / (4 * BLOCK) + 1; ++it) {
        int i = tid + it * BLOCK;
        if (i < out_f4)
            outv[i] = ldso[i];
    }
    if (tid < out_rem) {
        int i = out_f4 * 4 + tid;
        (out + block_row * XCDIM)[i] = lds_tile[i];
    }
}

extern "C" void kernel_launch(void* const* d_in, const int* in_sizes, int n_in,
                              void* d_out, int out_size, void* d_ws, size_t ws_size,
                              hipStream_t stream) {
    const float* x = (const float*)d_in[0];
    const float* table = (const float*)d_in[1];
    float* out = (float*)d_out;
    const int batch = in_sizes[0] / XDIM; // 1048576
    const int grid = (batch + ROWS_PER_BLOCK - 1) / ROWS_PER_BLOCK; // 4096
    twohot_argmax_kernel<<<grid, BLOCK, 0, stream>>>(x, table, out, batch);
}

// Round 3
// 268.043 us; speedup vs baseline: 1.0421x; 1.0421x over previous
//
#include <hip/hip_runtime.h>

#define XDIM 45
#define XCDIM 10
#define RPB 256      // rows per block
#define BLOCK 256

typedef float v4f __attribute__((ext_vector_type(4))); // clang-native: OK for nontemporal builtins

// Two-hot code idx -> pair of one-positions (a,b): a = 9-g where
// g(g-1)/2 <= idx < g(g+1)/2, b = 9-(idx - g(g-1)/2). Derived from the
// reference generator (colex enumeration of C(10,2)); verified by hand
// simulation incl. tail-reversal steps at group boundaries.

__global__ __launch_bounds__(BLOCK) void twohot_argmax_kernel(
    const float* __restrict__ x,
    float* __restrict__ out,
    int batch)
{
    __shared__ float lds_tile[RPB * XDIM]; // 46080 B, reused for out staging

    const int tid = threadIdx.x;
    const long long block_row = (long long)blockIdx.x * RPB;
    const int rows_here = (int)min((long long)RPB, (long long)batch - block_row);

    // ---- stage x tile into LDS, coalesced 16B loads (tile base 46080B-aligned)
    const float* xbase = x + block_row * XDIM;
    const int nf = rows_here * XDIM;
    const int nf4 = nf >> 2;          // full block: 2880
    const int nrem = nf & 3;          // full block: 0
    const v4f* __restrict__ xin = (const v4f*)xbase;
    v4f* ldsv = (v4f*)lds_tile;
    #pragma unroll
    for (int it = 0; it < (RPB * XDIM) / (4 * BLOCK) + 1; ++it) { // 12 iters
        int i = tid + it * BLOCK;
        if (i < nf4)
            ldsv[i] = __builtin_nontemporal_load(&xin[i]);
    }
    if (tid < nrem)
        lds_tile[nf4 * 4 + tid] = xbase[nf4 * 4 + tid];
    __syncthreads();

    // ---- per-thread argmax of its own row (strict > == first-max, jnp.argmax)
    unsigned mask = 0;
    if (tid < rows_here) {
        const float* row = lds_tile + tid * XDIM; // stride 45 (odd): free 2-way LDS aliasing
        float m = row[0];
        int best = 0;
        #pragma unroll
        for (int k = 1; k < XDIM; ++k) {
            float v = row[k];
            if (v > m) { m = v; best = k; }
        }
        int g = 1 + (best >= 1) + (best >= 3) + (best >= 6) + (best >= 10)
                  + (best >= 15) + (best >= 21) + (best >= 28) + (best >= 36);
        int kk = best - (g * (g - 1)) / 2;
        mask = (1u << (9 - g)) | (1u << (9 - kk));
    }
    __syncthreads(); // input-tile reads done before reuse

    // ---- write two-hot row into LDS out-staging, 5x ds_write_b64
    if (tid < rows_here) {
        float2* o2 = (float2*)(lds_tile + tid * XCDIM); // 40B base: 8-aligned
        #pragma unroll
        for (int j = 0; j < 5; ++j) {
            float2 p;
            p.x = ((mask >> (2 * j)) & 1u) ? 1.0f : 0.0f;
            p.y = ((mask >> (2 * j + 1)) & 1u) ? 1.0f : 0.0f;
            o2[j] = p;
        }
    }
    __syncthreads();

    // ---- coalesced 16B store of the out tile
    v4f* __restrict__ outv = (v4f*)(out + block_row * XCDIM);
    const int of = rows_here * XCDIM;
    const int of4 = of >> 2;          // full block: 640
    const int orem = of & 3;          // full block: 0
    const v4f* ldso = (const v4f*)lds_tile;
    #pragma unroll
    for (int it = 0; it < (RPB * XCDIM) / (4 * BLOCK) + 1; ++it) { // 3 iters
        int i = tid + it * BLOCK;
        if (i < of4)
            __builtin_nontemporal_store(ldso[i], &outv[i]);
    }
    if (tid < orem)
        (out + block_row * XCDIM)[of4 * 4 + tid] = lds_tile[of4 * 4 + tid];
}

extern "C" void kernel_launch(void* const* d_in, const int* in_sizes, int n_in,
                              void* d_out, int out_size, void* d_ws, size_t ws_size,
                              hipStream_t stream) {
    const float* x = (const float*)d_in[0];
    // d_in[1] (twohot_table) unused: codes computed arithmetically.
    float* out = (float*)d_out;
    const int batch = in_sizes[0] / XDIM; // 1048576
    const int grid = (batch + RPB - 1) / RPB; // 4096
    twohot_argmax_kernel<<<grid, BLOCK, 0, stream>>>(x, out, batch);
}